// Round 1
// baseline (6282.987 us; speedup 1.0000x reference)
//
#include <hip/hip_runtime.h>
#include <hip/hip_bf16.h>
#include <stdint.h>

// Problem constants
#define B_    256
#define T_    128
#define W_    32
#define H_    512
#define G4_   2048   // 4*H
#define TW_   96     // warm steps
#define STEPS_ 191   // 96 warm + 95 decode cells
#define TEAMS 8
#define MEMBERS 32
#define ROWS  32     // batch rows per team
#define HC    16     // h-columns per block

typedef __attribute__((ext_vector_type(8))) short short8;
typedef __attribute__((ext_vector_type(4))) float f32x4;

__device__ __forceinline__ unsigned short f2bf(float f) {
  uint32_t u = __float_as_uint(f);
  u += 0x7fffu + ((u >> 16) & 1u);   // round-to-nearest-even
  return (unsigned short)(u >> 16);
}
__device__ __forceinline__ float sigm(float x) { return 1.f / (1.f + __expf(-x)); }
__device__ __forceinline__ float tanh_(float x) { return 1.f - 2.f / (1.f + __expf(2.f * x)); }

// ---------------------------------------------------------------------------
// Persistent LSTM kernel. 256 blocks x 256 threads (all co-resident).
// team = blockIdx&7 (rows team*32..+32), member = blockIdx>>3 (hcols member*16..+16)
// Wave w of each block owns gate w (i,f,g,o). Wr slice lives in VGPRs as
// pre-packed MFMA B-fragments. h exchanged via double-buffered global bufs +
// per-team flag barrier (device scope release/acquire).
// ---------------------------------------------------------------------------
__global__ __launch_bounds__(256, 1) void lstm_kernel(
    const float* __restrict__ inputs, const float* __restrict__ Wk,
    const float* __restrict__ Wr, const float* __restrict__ bias,
    const float* __restrict__ Ww, const float* __restrict__ bw,
    unsigned short* __restrict__ h0buf, unsigned short* __restrict__ h1buf,
    unsigned short* __restrict__ warm, int* __restrict__ flags,
    float* __restrict__ out_pred)
{
  const int team = blockIdx.x & 7;
  const int member = blockIdx.x >> 3;
  const int rbase = team * ROWS;
  const int hbase = member * HC;
  const int tid = threadIdx.x;
  const int wave = tid >> 6;
  const int lane = tid & 63;
  const int l4 = lane >> 4, l16 = lane & 15;

  __shared__ float x_lds[ROWS][2];
  __shared__ float z_lds[4][2][16][16];   // [gate][mtile][col][row16]
  __shared__ float c_lds[ROWS][HC];
  __shared__ float ww_lds[H_][2];

  for (int i = tid; i < H_; i += 256) { ww_lds[i][0] = Ww[2*i]; ww_lds[i][1] = Ww[2*i+1]; }
  for (int i = tid; i < ROWS*HC; i += 256) ((float*)c_lds)[i] = 0.f;

  const int g = wave;                       // gate index
  const int gc = g * H_ + hbase + l16;      // gate column in [0,2048)
  const float wk0 = Wk[gc], wk1 = Wk[G4_ + gc], bb = bias[gc];

  // B-fragments: lane holds Wr[k = ks*32 + l4*8 + j][gc], j=0..7
  short8 bfrag[16];
#pragma unroll
  for (int ks = 0; ks < 16; ks++) {
    const float* wp = Wr + (size_t)(ks*32 + l4*8) * G4_ + gc;
#pragma unroll
    for (int j = 0; j < 8; j++) bfrag[ks][j] = (short)f2bf(wp[(size_t)j * G4_]);
  }
  __syncthreads();

  int* tflags = flags + team * MEMBERS;

  for (int t = 0; t < STEPS_; t++) {
    const unsigned short* hprev = (t & 1) ? h1buf : h0buf;
    unsigned short* hnext = (t & 1) ? h0buf : h1buf;

    // ---- x phase: warm inputs, or pred = h_prev @ Ww + bw (decoder) ----
    if (t < TW_) {
      if (tid < ROWS*2) {
        int row = tid >> 1, cc = tid & 1;
        x_lds[row][cc] = inputs[(size_t)(rbase+row)*(T_*2) + (W_ + t)*2 + cc];
      }
    } else {
      int row = tid >> 3, seg = tid & 7;
      const unsigned short* hr = hprev + (size_t)(rbase+row)*H_ + seg*64;
      float p0 = 0.f, p1 = 0.f;
#pragma unroll
      for (int i = 0; i < 8; i++) {
        uint4 u = *(const uint4*)(hr + i*8);
        uint32_t uu[4] = {u.x, u.y, u.z, u.w};
#pragma unroll
        for (int q = 0; q < 4; q++) {
          float hlo = __uint_as_float(uu[q] << 16);
          float hhi = __uint_as_float(uu[q] & 0xffff0000u);
          int k = seg*64 + i*8 + q*2;
          p0 += hlo * ww_lds[k][0];   p1 += hlo * ww_lds[k][1];
          p0 += hhi * ww_lds[k+1][0]; p1 += hhi * ww_lds[k+1][1];
        }
      }
      p0 += __shfl_xor(p0, 1); p1 += __shfl_xor(p1, 1);
      p0 += __shfl_xor(p0, 2); p1 += __shfl_xor(p1, 2);
      p0 += __shfl_xor(p0, 4); p1 += __shfl_xor(p1, 4);
      if (seg == 0) {
        p0 += bw[0]; p1 += bw[1];
        x_lds[row][0] = p0; x_lds[row][1] = p1;
        if (member == 0) {
          size_t off = ((size_t)(rbase+row)*96 + (t - TW_)) * 2;
          out_pred[off] = p0; out_pred[off+1] = p1;
        }
      }
    }
    __syncthreads();

    // ---- z = x@Wk + b + h@Wr  (MFMA over K=512) ----
    f32x4 acc0, acc1;
#pragma unroll
    for (int j = 0; j < 4; j++) {
      int r0 = l4*4 + j;
      acc0[j] = bb + wk0 * x_lds[r0][0]    + wk1 * x_lds[r0][1];
      acc1[j] = bb + wk0 * x_lds[16+r0][0] + wk1 * x_lds[16+r0][1];
    }
    const unsigned short* hp = hprev + (size_t)rbase * H_;
#pragma unroll
    for (int ks = 0; ks < 16; ks++) {
      short8 a0 = *(const short8*)(hp + (size_t)l16*H_      + ks*32 + l4*8);
      short8 a1 = *(const short8*)(hp + (size_t)(16+l16)*H_ + ks*32 + l4*8);
      acc0 = __builtin_amdgcn_mfma_f32_16x16x32_bf16(a0, bfrag[ks], acc0, 0, 0, 0);
      acc1 = __builtin_amdgcn_mfma_f32_16x16x32_bf16(a1, bfrag[ks], acc1, 0, 0, 0);
    }
    *(f32x4*)&z_lds[g][0][l16][l4*4] = acc0;
    *(f32x4*)&z_lds[g][1][l16][l4*4] = acc1;
    __syncthreads();

    // ---- cell update: 512 elems, 2 per thread ----
    {
      int row = tid >> 3, mt = row >> 4, r16 = row & 15;
      int c0 = (tid & 7) * 2;
      unsigned short* hw = hnext + (size_t)(rbase+row)*H_ + hbase + c0;
      unsigned short* wwp = warm + (size_t)(rbase+row)*H_ + hbase + c0;
      unsigned short hv2[2];
#pragma unroll
      for (int e = 0; e < 2; e++) {
        int col = c0 + e;
        float zi = z_lds[0][mt][col][r16];
        float zf = z_lds[1][mt][col][r16];
        float zg = z_lds[2][mt][col][r16];
        float zo = z_lds[3][mt][col][r16];
        float cold = c_lds[row][col];
        float cn = sigm(zf) * cold + sigm(zi) * tanh_(zg);
        float hn = sigm(zo) * tanh_(cn);
        c_lds[row][col] = cn;
        hv2[e] = f2bf(hn);
      }
      uint32_t packed = (uint32_t)hv2[0] | ((uint32_t)hv2[1] << 16);
      *(uint32_t*)hw = packed;
      if (t == TW_ - 1) *(uint32_t*)wwp = packed;   // warm_out snapshot
    }

    // ---- team barrier ----
    __threadfence();
    __syncthreads();
    if (tid == 0)
      __hip_atomic_store(&tflags[member], t+1, __ATOMIC_RELEASE, __HIP_MEMORY_SCOPE_AGENT);
    if (tid < MEMBERS) {
      while (__hip_atomic_load(&tflags[tid], __ATOMIC_ACQUIRE, __HIP_MEMORY_SCOPE_AGENT) < t+1) {
        __builtin_amdgcn_s_sleep(1);
      }
    }
    __syncthreads();
  }

  // ---- final pred (k=95) from h after step 190 (lives in h1buf) ----
  if (member == 0) {
    const unsigned short* hr0 = h1buf;
    int row = tid >> 3, seg = tid & 7;
    const unsigned short* hr = hr0 + (size_t)(rbase+row)*H_ + seg*64;
    float p0 = 0.f, p1 = 0.f;
#pragma unroll
    for (int i = 0; i < 8; i++) {
      uint4 u = *(const uint4*)(hr + i*8);
      uint32_t uu[4] = {u.x, u.y, u.z, u.w};
#pragma unroll
      for (int q = 0; q < 4; q++) {
        float hlo = __uint_as_float(uu[q] << 16);
        float hhi = __uint_as_float(uu[q] & 0xffff0000u);
        int k = seg*64 + i*8 + q*2;
        p0 += hlo * ww_lds[k][0];   p1 += hlo * ww_lds[k][1];
        p0 += hhi * ww_lds[k+1][0]; p1 += hhi * ww_lds[k+1][1];
      }
    }
    p0 += __shfl_xor(p0, 1); p1 += __shfl_xor(p1, 1);
    p0 += __shfl_xor(p0, 2); p1 += __shfl_xor(p1, 2);
    p0 += __shfl_xor(p0, 4); p1 += __shfl_xor(p1, 4);
    if (seg == 0) {
      size_t off = ((size_t)(rbase+row)*96 + 95) * 2;
      out_pred[off] = p0 + bw[0]; out_pred[off+1] = p1 + bw[1];
    }
  }
}

// ---------------------------------------------------------------------------
// cat = [warm_out (bf16) | relu(inputs[:, :31] @ Wc + bc)] as bf16 [256][16384]
// ---------------------------------------------------------------------------
__global__ void build_cat_kernel(
    const float* __restrict__ inputs, const float* __restrict__ Wc,
    const float* __restrict__ bc, const unsigned short* __restrict__ warm,
    unsigned short* __restrict__ cat)
{
  int idx = (blockIdx.x * 256 + threadIdx.x) * 4;   // 4096 blocks
  int b = idx >> 14, k0 = idx & 16383;
  uint2 out;
  if (k0 < 512) {
    out = *(const uint2*)(warm + (size_t)b*512 + k0);
  } else {
    int kk = k0 - 512;
    int w = kk >> 9;
    int hc = kk & 511;
    float x0 = inputs[(size_t)b*256 + w*2], x1 = inputs[(size_t)b*256 + w*2 + 1];
    unsigned short v[4];
#pragma unroll
    for (int j = 0; j < 4; j++) {
      float val = x0 * Wc[hc+j] + x1 * Wc[512 + hc + j] + bc[hc+j];
      v[j] = f2bf(fmaxf(val, 0.f));
    }
    out.x = (uint32_t)v[0] | ((uint32_t)v[1] << 16);
    out.y = (uint32_t)v[2] | ((uint32_t)v[3] << 16);
  }
  *(uint2*)(cat + idx) = out;
}

// ---------------------------------------------------------------------------
// Transposed GEMM: partialT[kc][n][b] = sum_k Wcc[k][n]*cat[b][k] over k-chunk.
// A' = Wcc^T (gathered, exactly-once from HBM), B' = cat^T (contig 16B loads).
// grid = 8 kchunks x 16 nchunks = 128 blocks x 256 thr. No LDS needed.
// ---------------------------------------------------------------------------
__global__ __launch_bounds__(256, 1) void gemm_kernel(
    const unsigned short* __restrict__ cat, const float* __restrict__ Wcc,
    float* __restrict__ partialT)
{
  const int nc = blockIdx.x & 15;
  const int kc = blockIdx.x >> 4;
  const int tid = threadIdx.x;
  const int w = tid >> 6, lane = tid & 63;
  const int l4 = lane >> 4, l16 = lane & 15;

  f32x4 zero = {0.f, 0.f, 0.f, 0.f};
  f32x4 acc[16];
#pragma unroll
  for (int i = 0; i < 16; i++) acc[i] = zero;

  const int kbase = kc * 2048;
  const int nrow = nc*64 + w*16 + l16;

  for (int ks = 0; ks < 64; ks++) {
    const float* wp = Wcc + (size_t)(kbase + ks*32 + l4*8) * 1024 + nrow;
    short8 af;
#pragma unroll
    for (int j = 0; j < 8; j++) af[j] = (short)f2bf(wp[(size_t)j * 1024]);
    const unsigned short* cp = cat + kbase + ks*32 + l4*8;
#pragma unroll
    for (int bt = 0; bt < 16; bt++) {
      short8 bf = *(const short8*)(cp + (size_t)(bt*16 + l16) * 16384);
      acc[bt] = __builtin_amdgcn_mfma_f32_16x16x32_bf16(af, bf, acc[bt], 0, 0, 0);
    }
  }

  float* pp = partialT + (size_t)kc*1024*256 + (size_t)(nc*64 + w*16 + l4*4)*256 + l16;
#pragma unroll
  for (int bt = 0; bt < 16; bt++) {
#pragma unroll
    for (int r = 0; r < 4; r++)
      pp[(size_t)r*256 + bt*16] = acc[bt][r];
  }
}

// ctT[n][b] = relu(bcc[n] + sum_p partialT[p][n][b])
__global__ void reduce_kernel(const float* __restrict__ partialT,
                              const float* __restrict__ bcc, float* __restrict__ ctT)
{
  int e = blockIdx.x * 256 + threadIdx.x;   // 1024 blocks
  int n = e >> 8;
  float s = bcc[n];
#pragma unroll
  for (int p = 0; p < 8; p++) s += partialT[(size_t)p*262144 + e];
  ctT[e] = fmaxf(s, 0.f);
}

// cost/prob heads: one wave per batch row
__global__ void head_kernel(const float* __restrict__ ctT, const float* __restrict__ Wp,
                            const float* __restrict__ bp, const float* __restrict__ Wco,
                            const float* __restrict__ bco, float* __restrict__ out)
{
  int b = blockIdx.x;
  int lane = threadIdx.x;
  float p0 = 0.f, p1 = 0.f, pc = 0.f;
#pragma unroll
  for (int i = 0; i < 16; i++) {
    int n = i*64 + lane;
    float c = ctT[(size_t)n*256 + b];
    p0 += c * Wp[2*n]; p1 += c * Wp[2*n+1]; pc += c * Wco[n];
  }
  for (int m = 1; m < 64; m <<= 1) {
    p0 += __shfl_xor(p0, m); p1 += __shfl_xor(p1, m); pc += __shfl_xor(pc, m);
  }
  if (lane == 0) {
    out[49152 + b]       = pc + bco[0];
    out[49408 + 2*b]     = 1.f / (1.f + __expf(-(p0 + bp[0])));
    out[49408 + 2*b + 1] = 1.f / (1.f + __expf(-(p1 + bp[1])));
  }
}

// ---------------------------------------------------------------------------
extern "C" void kernel_launch(void* const* d_in, const int* in_sizes, int n_in,
                              void* d_out, int out_size, void* d_ws, size_t ws_size,
                              hipStream_t stream) {
  const float* inputs = (const float*)d_in[0];
  const float* Wk   = (const float*)d_in[1];
  const float* Wr   = (const float*)d_in[2];
  const float* bias = (const float*)d_in[3];
  const float* Ww   = (const float*)d_in[4];
  const float* bw   = (const float*)d_in[5];
  const float* Wc   = (const float*)d_in[6];
  const float* bc   = (const float*)d_in[7];
  const float* Wcc  = (const float*)d_in[8];
  const float* bcc  = (const float*)d_in[9];
  const float* Wp   = (const float*)d_in[10];
  const float* bp   = (const float*)d_in[11];
  const float* Wco  = (const float*)d_in[12];
  const float* bco  = (const float*)d_in[13];
  float* out = (float*)d_out;
  char* ws = (char*)d_ws;

  // ws layout (offsets bytes):
  // [0x000000) h0 buf   256KB
  // [0x040000) flags    4KB  (8 teams x 32 members ints)
  // [0x041000) h1 buf   256KB
  // [0x081000) warm     256KB (bf16 warm_out)
  // [0x0C1000) cat      8MB   (bf16 [256][16384])
  // [0x8C1000) partialT 8MB   ([8][1024][256] f32)
  // [0x10C1000) ctT     1MB   ([1024][256] f32)
  unsigned short* h0   = (unsigned short*)(ws);
  int*            flags= (int*)(ws + 0x40000);
  unsigned short* h1   = (unsigned short*)(ws + 0x41000);
  unsigned short* warm = (unsigned short*)(ws + 0x81000);
  unsigned short* cat  = (unsigned short*)(ws + 0xC1000);
  float*          partialT = (float*)(ws + 0x8C1000);
  float*          ctT  = (float*)(ws + 0x10C1000);

  // zero h0 + flags (must be re-done every launch; ws not re-poisoned between replays)
  hipMemsetAsync(d_ws, 0, 0x41000, stream);

  lstm_kernel<<<256, 256, 0, stream>>>(inputs, Wk, Wr, bias, Ww, bw,
                                       h0, h1, warm, flags, out);
  build_cat_kernel<<<4096, 256, 0, stream>>>(inputs, Wc, bc, warm, cat);
  gemm_kernel<<<128, 256, 0, stream>>>(cat, Wcc, partialT);
  reduce_kernel<<<1024, 256, 0, stream>>>(partialT, bcc, ctT);
  head_kernel<<<256, 64, 0, stream>>>(ctT, Wp, bp, Wco, bco, out);

  // inputs passthrough (output 3), offset 49920 floats
  hipMemcpyAsync(out + 49920, inputs, (size_t)65536 * sizeof(float),
                 hipMemcpyDeviceToDevice, stream);
}

// Round 2
// 1098.151 us; speedup vs baseline: 5.7214x; 5.7214x over previous
//
#include <hip/hip_runtime.h>
#include <hip/hip_bf16.h>
#include <stdint.h>

// Problem constants
#define B_    256
#define T_    128
#define W_    32
#define H_    512
#define G4_   2048   // 4*H
#define TW_   96     // warm steps
#define STEPS_ 191   // 96 warm + 95 decode cells
#define TEAMS 8
#define MEMBERS 16
#define ROWS  32     // batch rows per team
#define HC    32     // h-columns per block (per gate)

typedef __attribute__((ext_vector_type(8))) short short8;
typedef __attribute__((ext_vector_type(4))) float f32x4;

__device__ __forceinline__ unsigned short f2bf(float f) {
  uint32_t u = __float_as_uint(f);
  u += 0x7fffu + ((u >> 16) & 1u);   // round-to-nearest-even
  return (unsigned short)(u >> 16);
}
__device__ __forceinline__ float sigm(float x) { return 1.f / (1.f + __expf(-x)); }
__device__ __forceinline__ float tanh_(float x) { return 1.f - 2.f / (1.f + __expf(2.f * x)); }

// Coherent (device-scope, cache-bypassing) accesses WITHOUT fence instructions.
// Relaxed agent atomics compile to global_load/store ... sc0 sc1 — they go to
// the device coherence point; no buffer_wbl2/buffer_inv is ever emitted.
#define LOAD_C64(p)    __hip_atomic_load((p), __ATOMIC_RELAXED, __HIP_MEMORY_SCOPE_AGENT)
#define STORE_C64(p,v) __hip_atomic_store((p), (v), __ATOMIC_RELAXED, __HIP_MEMORY_SCOPE_AGENT)
#define STORE_C32(p,v) __hip_atomic_store((p), (v), __ATOMIC_RELAXED, __HIP_MEMORY_SCOPE_AGENT)

// ww_lds skewed index: k stride 64 hits distinct banks
__device__ __forceinline__ int wwidx(int k, int c) { return k*2 + c + (k>>6)*4; }

// ---------------------------------------------------------------------------
// Persistent LSTM kernel. 128 blocks x 256 threads (co-resident at 1 blk/CU).
// team = blockIdx&7 (rows team*32..+32), member = blockIdx>>3 (32 hcols each)
// Wave w owns gate w; Wr slice (512 x 2*16 cols per gate) pre-packed in VGPRs.
// h exchanged via double-buffered global bufs with relaxed sc0sc1 atomics +
// manual vmcnt(0) release + per-team flag barrier. No L2 flush/inv anywhere.
// ---------------------------------------------------------------------------
__global__ __launch_bounds__(256, 1) void lstm_kernel(
    const float* __restrict__ inputs, const float* __restrict__ Wk,
    const float* __restrict__ Wr, const float* __restrict__ bias,
    const float* __restrict__ Ww, const float* __restrict__ bw,
    unsigned short* __restrict__ h0buf, unsigned short* __restrict__ h1buf,
    unsigned short* __restrict__ warm, int* __restrict__ flags,
    float* __restrict__ out_pred)
{
  const int team = blockIdx.x & 7;
  const int member = blockIdx.x >> 3;   // 0..15
  const int rbase = team * ROWS;
  const int hbase = member * HC;        // 0..480
  const int tid = threadIdx.x;
  const int wave = tid >> 6;
  const int lane = tid & 63;
  const int l4 = lane >> 4, l16 = lane & 15;

  __shared__ unsigned short h_lds[ROWS][H_];   // 32KB, granule-XOR swizzled
  __shared__ float z_lds[4][2][HC][20];        // padded inner: conflict-free
  __shared__ float c_lds[ROWS][HC + 1];
  __shared__ float x_lds[ROWS][2];
  __shared__ float ww_lds[H_ * 2 + 32];        // skewed layout via wwidx()

  for (int i = tid; i < H_; i += 256) {
    ww_lds[wwidx(i, 0)] = Ww[2*i];
    ww_lds[wwidx(i, 1)] = Ww[2*i + 1];
  }
  for (int i = tid; i < ROWS*(HC+1); i += 256) ((float*)c_lds)[i] = 0.f;

  const int g = wave;                   // gate index (i,f,g,o)
  float wk0[2], wk1[2], bb[2];
  short8 bfrag[2][16];                  // 128 VGPRs of Wr, persistent
#pragma unroll
  for (int nt = 0; nt < 2; nt++) {
    int gc = g*H_ + hbase + nt*16 + l16;
    wk0[nt] = Wk[gc]; wk1[nt] = Wk[G4_ + gc]; bb[nt] = bias[gc];
#pragma unroll
    for (int ks = 0; ks < 16; ks++) {
      const float* wp = Wr + (size_t)(ks*32 + l4*8) * G4_ + gc;
#pragma unroll
      for (int j = 0; j < 8; j++) bfrag[nt][ks][j] = (short)f2bf(wp[(size_t)j * G4_]);
    }
  }
  __syncthreads();

  int* tflags = flags + team * MEMBERS;
  const int srow = tid >> 3, sg = tid & 7;    // staging/pred decomposition

  for (int t = 0; t < STEPS_; t++) {
    const unsigned short* hprev = (t & 1) ? h1buf : h0buf;
    unsigned short* hnext = (t & 1) ? h0buf : h1buf;

    // ---- stage hprev team slice -> LDS (coherent loads, XOR swizzle) ----
    {
      const uint64_t* src = (const uint64_t*)(hprev + (size_t)(rbase+srow)*H_ + sg*8);
      uint64_t q[16];
#pragma unroll
      for (int i = 0; i < 8; i++) {
        q[2*i]   = LOAD_C64(src + (size_t)i*16);
        q[2*i+1] = LOAD_C64(src + (size_t)i*16 + 1);
      }
#pragma unroll
      for (int i = 0; i < 8; i++) {
        int gr = sg + 8*i;                              // logical 16B granule
        uint64_t* d = (uint64_t*)&h_lds[srow][(gr ^ (srow & 7)) * 8];
        d[0] = q[2*i]; d[1] = q[2*i+1];
      }
    }
    __syncthreads();

    // ---- x phase: warm inputs, or pred = h_prev @ Ww + bw (from LDS) ----
    if (t < TW_) {
      if (tid < ROWS*2) {
        int row = tid >> 1, cc = tid & 1;
        x_lds[row][cc] = inputs[(size_t)(rbase+row)*(T_*2) + (W_ + t)*2 + cc];
      }
    } else {
      float p0 = 0.f, p1 = 0.f;
#pragma unroll
      for (int i = 0; i < 8; i++) {
        uint4 u = *(const uint4*)&h_lds[srow][((sg*8 + i) ^ (srow & 7)) * 8];
        uint32_t uu[4] = {u.x, u.y, u.z, u.w};
#pragma unroll
        for (int q = 0; q < 4; q++) {
          float hlo = __uint_as_float(uu[q] << 16);
          float hhi = __uint_as_float(uu[q] & 0xffff0000u);
          int k = sg*64 + i*8 + q*2;
          p0 += hlo * ww_lds[wwidx(k,0)];   p1 += hlo * ww_lds[wwidx(k,1)];
          p0 += hhi * ww_lds[wwidx(k+1,0)]; p1 += hhi * ww_lds[wwidx(k+1,1)];
        }
      }
      p0 += __shfl_xor(p0, 1); p1 += __shfl_xor(p1, 1);
      p0 += __shfl_xor(p0, 2); p1 += __shfl_xor(p1, 2);
      p0 += __shfl_xor(p0, 4); p1 += __shfl_xor(p1, 4);
      if (sg == 0) {
        p0 += bw[0]; p1 += bw[1];
        x_lds[srow][0] = p0; x_lds[srow][1] = p1;
        if (member == 0) {
          size_t off = ((size_t)(rbase+srow)*96 + (t - TW_)) * 2;
          out_pred[off] = p0; out_pred[off+1] = p1;
        }
      }
    }
    __syncthreads();

    // ---- z = x@Wk + b + h@Wr  (MFMA over K=512, fragments from LDS) ----
    f32x4 acc[2][2];
#pragma unroll
    for (int nt = 0; nt < 2; nt++)
#pragma unroll
      for (int mt = 0; mt < 2; mt++)
#pragma unroll
        for (int j = 0; j < 4; j++) {
          int r = mt*16 + l4*4 + j;
          acc[nt][mt][j] = bb[nt] + wk0[nt]*x_lds[r][0] + wk1[nt]*x_lds[r][1];
        }
#pragma unroll
    for (int ks = 0; ks < 16; ks++) {
      int pg = ((ks*4 + l4) ^ (l16 & 7)) * 8;          // swizzled granule
      short8 a0 = *(const short8*)&h_lds[l16][pg];
      short8 a1 = *(const short8*)&h_lds[16 + l16][pg];
      acc[0][0] = __builtin_amdgcn_mfma_f32_16x16x32_bf16(a0, bfrag[0][ks], acc[0][0], 0,0,0);
      acc[0][1] = __builtin_amdgcn_mfma_f32_16x16x32_bf16(a1, bfrag[0][ks], acc[0][1], 0,0,0);
      acc[1][0] = __builtin_amdgcn_mfma_f32_16x16x32_bf16(a0, bfrag[1][ks], acc[1][0], 0,0,0);
      acc[1][1] = __builtin_amdgcn_mfma_f32_16x16x32_bf16(a1, bfrag[1][ks], acc[1][1], 0,0,0);
    }
#pragma unroll
    for (int nt = 0; nt < 2; nt++)
#pragma unroll
      for (int mt = 0; mt < 2; mt++)
        *(f32x4*)&z_lds[g][mt][nt*16 + l16][l4*4] = acc[nt][mt];
    __syncthreads();

    // ---- cell update: 32 rows x 32 cols, 4 cols/thread ----
    {
      int row = tid & 31, mt = row >> 4, r16 = row & 15;
      int c0 = (tid >> 5) * 4;
      unsigned short hv[4];
#pragma unroll
      for (int e = 0; e < 4; e++) {
        int col = c0 + e;
        float zi = z_lds[0][mt][col][r16];
        float zf = z_lds[1][mt][col][r16];
        float zg = z_lds[2][mt][col][r16];
        float zo = z_lds[3][mt][col][r16];
        float cold = c_lds[row][col];
        float cn = sigm(zf) * cold + sigm(zi) * tanh_(zg);
        float hn = sigm(zo) * tanh_(cn);
        c_lds[row][col] = cn;
        hv[e] = f2bf(hn);
      }
      uint64_t packed = (uint64_t)hv[0] | ((uint64_t)hv[1] << 16)
                      | ((uint64_t)hv[2] << 32) | ((uint64_t)hv[3] << 48);
      uint64_t* hw = (uint64_t*)(hnext + (size_t)(rbase+row)*H_ + hbase + c0);
      STORE_C64(hw, packed);
      if (t == TW_ - 1)
        *(uint64_t*)(warm + (size_t)(rbase+row)*H_ + hbase + c0) = packed;
    }

    // ---- team barrier: manual release (vmcnt drain) + flag + poll ----
    asm volatile("s_waitcnt vmcnt(0)" ::: "memory");   // h stores at coherence pt
    __syncthreads();                                    // all waves drained
    if (tid == 0)
      STORE_C32(&tflags[member], t + 1);
    if (tid < 8) {
      const uint64_t* fp = (const uint64_t*)tflags + tid;  // 2 flags per thread
      uint32_t need = (uint32_t)(t + 1);
      for (;;) {
        uint64_t v = LOAD_C64(fp);
        if ((uint32_t)v >= need && (uint32_t)(v >> 32) >= need) break;
        __builtin_amdgcn_s_sleep(1);
      }
    }
    __syncthreads();
  }

  // ---- final pred (k=95) from h after step 190 (in h1buf) ----
  if (member == 0) {
    const uint64_t* hr = (const uint64_t*)(h1buf + (size_t)(rbase+srow)*H_ + sg*64);
    uint64_t qq[16];
#pragma unroll
    for (int i = 0; i < 16; i++) qq[i] = LOAD_C64(hr + i);
    float p0 = 0.f, p1 = 0.f;
#pragma unroll
    for (int i = 0; i < 16; i++) {
      uint32_t lo = (uint32_t)qq[i], hi = (uint32_t)(qq[i] >> 32);
      float h0f = __uint_as_float(lo << 16);
      float h1f = __uint_as_float(lo & 0xffff0000u);
      float h2f = __uint_as_float(hi << 16);
      float h3f = __uint_as_float(hi & 0xffff0000u);
      int k = sg*64 + i*4;
      p0 += h0f*ww_lds[wwidx(k,0)]   + h1f*ww_lds[wwidx(k+1,0)]
          + h2f*ww_lds[wwidx(k+2,0)] + h3f*ww_lds[wwidx(k+3,0)];
      p1 += h0f*ww_lds[wwidx(k,1)]   + h1f*ww_lds[wwidx(k+1,1)]
          + h2f*ww_lds[wwidx(k+2,1)] + h3f*ww_lds[wwidx(k+3,1)];
    }
    p0 += __shfl_xor(p0, 1); p1 += __shfl_xor(p1, 1);
    p0 += __shfl_xor(p0, 2); p1 += __shfl_xor(p1, 2);
    p0 += __shfl_xor(p0, 4); p1 += __shfl_xor(p1, 4);
    if (sg == 0) {
      size_t off = ((size_t)(rbase+srow)*96 + 95) * 2;
      out_pred[off] = p0 + bw[0]; out_pred[off+1] = p1 + bw[1];
    }
  }
}

// ---------------------------------------------------------------------------
// cat = [warm_out (bf16) | relu(inputs[:, :31] @ Wc + bc)] as bf16 [256][16384]
// ---------------------------------------------------------------------------
__global__ void build_cat_kernel(
    const float* __restrict__ inputs, const float* __restrict__ Wc,
    const float* __restrict__ bc, const unsigned short* __restrict__ warm,
    unsigned short* __restrict__ cat)
{
  int idx = (blockIdx.x * 256 + threadIdx.x) * 4;   // 4096 blocks
  int b = idx >> 14, k0 = idx & 16383;
  uint2 out;
  if (k0 < 512) {
    out = *(const uint2*)(warm + (size_t)b*512 + k0);
  } else {
    int kk = k0 - 512;
    int w = kk >> 9;
    int hc = kk & 511;
    float x0 = inputs[(size_t)b*256 + w*2], x1 = inputs[(size_t)b*256 + w*2 + 1];
    unsigned short v[4];
#pragma unroll
    for (int j = 0; j < 4; j++) {
      float val = x0 * Wc[hc+j] + x1 * Wc[512 + hc + j] + bc[hc+j];
      v[j] = f2bf(fmaxf(val, 0.f));
    }
    out.x = (uint32_t)v[0] | ((uint32_t)v[1] << 16);
    out.y = (uint32_t)v[2] | ((uint32_t)v[3] << 16);
  }
  *(uint2*)(cat + idx) = out;
}

// ---------------------------------------------------------------------------
// Transposed GEMM: partialT[kc][n][b] = sum_k Wcc[k][n]*cat[b][k] over k-chunk.
// ---------------------------------------------------------------------------
__global__ __launch_bounds__(256, 1) void gemm_kernel(
    const unsigned short* __restrict__ cat, const float* __restrict__ Wcc,
    float* __restrict__ partialT)
{
  const int nc = blockIdx.x & 15;
  const int kc = blockIdx.x >> 4;
  const int tid = threadIdx.x;
  const int w = tid >> 6, lane = tid & 63;
  const int l4 = lane >> 4, l16 = lane & 15;

  f32x4 zero = {0.f, 0.f, 0.f, 0.f};
  f32x4 acc[16];
#pragma unroll
  for (int i = 0; i < 16; i++) acc[i] = zero;

  const int kbase = kc * 2048;
  const int nrow = nc*64 + w*16 + l16;

  for (int ks = 0; ks < 64; ks++) {
    const float* wp = Wcc + (size_t)(kbase + ks*32 + l4*8) * 1024 + nrow;
    short8 af;
#pragma unroll
    for (int j = 0; j < 8; j++) af[j] = (short)f2bf(wp[(size_t)j * 1024]);
    const unsigned short* cp = cat + kbase + ks*32 + l4*8;
#pragma unroll
    for (int bt = 0; bt < 16; bt++) {
      short8 bf = *(const short8*)(cp + (size_t)(bt*16 + l16) * 16384);
      acc[bt] = __builtin_amdgcn_mfma_f32_16x16x32_bf16(af, bf, acc[bt], 0, 0, 0);
    }
  }

  float* pp = partialT + (size_t)kc*1024*256 + (size_t)(nc*64 + w*16 + l4*4)*256 + l16;
#pragma unroll
  for (int bt = 0; bt < 16; bt++) {
#pragma unroll
    for (int r = 0; r < 4; r++)
      pp[(size_t)r*256 + bt*16] = acc[bt][r];
  }
}

// ctT[n][b] = relu(bcc[n] + sum_p partialT[p][n][b])
__global__ void reduce_kernel(const float* __restrict__ partialT,
                              const float* __restrict__ bcc, float* __restrict__ ctT)
{
  int e = blockIdx.x * 256 + threadIdx.x;   // 1024 blocks
  int n = e >> 8;
  float s = bcc[n];
#pragma unroll
  for (int p = 0; p < 8; p++) s += partialT[(size_t)p*262144 + e];
  ctT[e] = fmaxf(s, 0.f);
}

// cost/prob heads: one wave per batch row
__global__ void head_kernel(const float* __restrict__ ctT, const float* __restrict__ Wp,
                            const float* __restrict__ bp, const float* __restrict__ Wco,
                            const float* __restrict__ bco, float* __restrict__ out)
{
  int b = blockIdx.x;
  int lane = threadIdx.x;
  float p0 = 0.f, p1 = 0.f, pc = 0.f;
#pragma unroll
  for (int i = 0; i < 16; i++) {
    int n = i*64 + lane;
    float c = ctT[(size_t)n*256 + b];
    p0 += c * Wp[2*n]; p1 += c * Wp[2*n+1]; pc += c * Wco[n];
  }
  for (int m = 1; m < 64; m <<= 1) {
    p0 += __shfl_xor(p0, m); p1 += __shfl_xor(p1, m); pc += __shfl_xor(pc, m);
  }
  if (lane == 0) {
    out[49152 + b]       = pc + bco[0];
    out[49408 + 2*b]     = 1.f / (1.f + __expf(-(p0 + bp[0])));
    out[49408 + 2*b + 1] = 1.f / (1.f + __expf(-(p1 + bp[1])));
  }
}

// ---------------------------------------------------------------------------
extern "C" void kernel_launch(void* const* d_in, const int* in_sizes, int n_in,
                              void* d_out, int out_size, void* d_ws, size_t ws_size,
                              hipStream_t stream) {
  const float* inputs = (const float*)d_in[0];
  const float* Wk   = (const float*)d_in[1];
  const float* Wr   = (const float*)d_in[2];
  const float* bias = (const float*)d_in[3];
  const float* Ww   = (const float*)d_in[4];
  const float* bw   = (const float*)d_in[5];
  const float* Wc   = (const float*)d_in[6];
  const float* bc   = (const float*)d_in[7];
  const float* Wcc  = (const float*)d_in[8];
  const float* bcc  = (const float*)d_in[9];
  const float* Wp   = (const float*)d_in[10];
  const float* bp   = (const float*)d_in[11];
  const float* Wco  = (const float*)d_in[12];
  const float* bco  = (const float*)d_in[13];
  float* out = (float*)d_out;
  char* ws = (char*)d_ws;

  // ws layout (offsets bytes):
  // [0x000000) h0 buf   256KB
  // [0x040000) flags    4KB (8 teams x 16 members ints)
  // [0x041000) h1 buf   256KB
  // [0x081000) warm     256KB (bf16 warm_out; only 256KB/2 used)
  // [0x0C1000) cat      8MB   (bf16 [256][16384])
  // [0x8C1000) partialT 8MB   ([8][1024][256] f32)
  // [0x10C1000) ctT     1MB   ([1024][256] f32)
  unsigned short* h0   = (unsigned short*)(ws);
  int*            flags= (int*)(ws + 0x40000);
  unsigned short* h1   = (unsigned short*)(ws + 0x41000);
  unsigned short* warm = (unsigned short*)(ws + 0x81000);
  unsigned short* cat  = (unsigned short*)(ws + 0xC1000);
  float*          partialT = (float*)(ws + 0x8C1000);
  float*          ctT  = (float*)(ws + 0x10C1000);

  // zero h0 + flags (re-done every launch; ws not re-poisoned between replays)
  hipMemsetAsync(d_ws, 0, 0x41000, stream);

  lstm_kernel<<<TEAMS*MEMBERS, 256, 0, stream>>>(inputs, Wk, Wr, bias, Ww, bw,
                                                 h0, h1, warm, flags, out);
  build_cat_kernel<<<4096, 256, 0, stream>>>(inputs, Wc, bc, warm, cat);
  gemm_kernel<<<128, 256, 0, stream>>>(cat, Wcc, partialT);
  reduce_kernel<<<1024, 256, 0, stream>>>(partialT, bcc, ctT);
  head_kernel<<<256, 64, 0, stream>>>(ctT, Wp, bp, Wco, bco, out);

  // inputs passthrough (output 3), offset 49920 floats
  hipMemcpyAsync(out + 49920, inputs, (size_t)65536 * sizeof(float),
                 hipMemcpyDeviceToDevice, stream);
}